// Round 1
// baseline (196.782 us; speedup 1.0000x reference)
//
#include <hip/hip_runtime.h>
#include <math.h>

#define NTOK 100
#define EDIM 5
#define NH   4
#define NL   3
#define DD   64
#define NWROW 300   // NW
#define BLK  256

// One workgroup per batch element. All layer state in LDS.
// Algebraic reduction: dots = out @ (scale*Wq^T Wk) @ out^T ; per-head 5x5 M.
//                      attn_out = sum_h attn_h @ out @ (Wv^T Wo_h^T) ; per-head 5x5 P.
__global__ __launch_bounds__(BLK, 4) void encoder_kernel(
    const float* __restrict__ x,
    const float* __restrict__ Wq,
    const float* __restrict__ Wk,
    const float* __restrict__ Wv,
    const float* __restrict__ Wo,
    const float* __restrict__ Wf,
    const float* __restrict__ bf,
    const float* __restrict__ g1,
    const float* __restrict__ b1,
    const float* __restrict__ g2,
    const float* __restrict__ b2,
    float* __restrict__ out)
{
  const int b = blockIdx.x;
  const int t = threadIdx.x;

  __shared__ float4 s_o4[NTOK];            // out[i][0..3]
  __shared__ float2 s_o2[NTOK];            // {out[i][4], mask_i}
  __shared__ float4 s_u4[NH][NTOK];        // u[h][j][0..3]
  __shared__ float  s_u1[NH][NTOK];        // u[h][j][4]
  __shared__ float  s_a [NH][NTOK][EDIM];  // a = out @ M_h (query side)
  __shared__ float  s_c [NH][NTOK][EDIM];  // per-head contrib
  __shared__ float  s_M [NL][NH][25];      // scale * Wq^T Wk
  __shared__ float  s_P [NL][NH][25];      // Wv^T Wo_h^T
  __shared__ float  s_x [NWROW];

  // ---- per-block M,P precompute (weights are tiny and L2/L1-hot) ----
  for (int r = t; r < 600; r += BLK) {
    int which = r / 300;
    int q  = r - which*300;
    int l  = q / 100;
    int q2 = q - l*100;
    int h  = q2 / 25;
    int q3 = q2 - h*25;
    int e  = q3 / 5, f = q3 - (q3/5)*5;
    float acc = 0.f;
    if (which == 0) {
      const float* wq = Wq + ((l*NH + h)*DD)*EDIM;
      const float* wk = Wk + ((l*NH + h)*DD)*EDIM;
      #pragma unroll 8
      for (int d = 0; d < DD; ++d) acc += wq[d*EDIM + e] * wk[d*EDIM + f];
      s_M[l][h][e*5+f] = acc * 0.125f;     // scale = 1/sqrt(64)
    } else {
      const float* wv = Wv + ((l*NH + h)*DD)*EDIM;
      const float* wo = Wo + (l*EDIM + f)*(NH*DD) + h*DD;  // f plays e'
      #pragma unroll 8
      for (int d = 0; d < DD; ++d) acc += wv[d*EDIM + e] * wo[d];
      s_P[l][h][e*5+f] = acc;
    }
  }

  // ---- load x row, build tokens: [kp0,kp1,kp2,sin(i),cos(i)] * mask ----
  for (int r = t; r < NWROW; r += BLK) s_x[r] = x[b*NWROW + r];
  __syncthreads();
  if (t < NTOK) {
    float k0 = s_x[3*t+0], k1 = s_x[3*t+1], k2 = s_x[3*t+2];
    float m  = (k2 > 0.f) ? 1.f : 0.f;
    float pos = (float)t;
    float sn = sinf(pos), cs = cosf(pos);
    s_o4[t] = make_float4(m*k0, m*k1, m*k2, m*sn);
    s_o2[t] = make_float2(m*cs, m);
  }
  __syncthreads();

  for (int l = 0; l < NL; ++l) {
    // ---- a = out @ M_h ; u = out @ P_h  (400 rows) ----
    for (int r = t; r < NH*NTOK; r += BLK) {
      int h = r / NTOK;
      int i = r - h*NTOK;
      float4 o4 = s_o4[i]; float2 o2 = s_o2[i];
      float o[5] = {o4.x, o4.y, o4.z, o4.w, o2.x};
      const float* Mh = s_M[l][h];
      const float* Ph = s_P[l][h];
      float a[5], u[5];
      #pragma unroll
      for (int f = 0; f < 5; ++f) {
        float av = 0.f, uv = 0.f;
        #pragma unroll
        for (int e = 0; e < 5; ++e) { av += o[e]*Mh[e*5+f]; uv += o[e]*Ph[e*5+f]; }
        a[f] = av; u[f] = uv;
      }
      #pragma unroll
      for (int f = 0; f < 5; ++f) s_a[h][i][f] = a[f];
      s_u4[h][i] = make_float4(u[0], u[1], u[2], u[3]);
      s_u1[h][i] = u[4];
    }
    __syncthreads();

    // ---- attention rows: one thread per (h,i), max-free softmax ----
    // masked query (mask_i==0): reference softmax over all -FLT_MAX -> uniform 1/N
    // masked key  (mask_j==0): p = 0 exactly (matches exp(-FLT_MAX - max) == 0)
    for (int r = t; r < NH*NTOK; r += BLK) {
      int h = r / NTOK;
      int i = r - h*NTOK;
      float a0 = s_a[h][i][0], a1 = s_a[h][i][1], a2 = s_a[h][i][2],
            a3 = s_a[h][i][3], a4 = s_a[h][i][4];
      float mi = s_o2[i].y;
      float c0=0.f,c1=0.f,c2=0.f,c3=0.f,c4=0.f,ls=0.f;
      #pragma unroll 4
      for (int j = 0; j < NTOK; ++j) {
        float4 oj  = s_o4[j];      // broadcast (wave-uniform address)
        float2 o2j = s_o2[j];
        float s = a0*oj.x + a1*oj.y + a2*oj.z + a3*oj.w + a4*o2j.x;
        float pex = __expf(s);
        float p = (mi != 0.f) ? ((o2j.y != 0.f) ? pex : 0.f) : 1.f;
        float4 u4 = s_u4[h][j];
        float  u1 = s_u1[h][j];
        ls += p;
        c0 += p*u4.x; c1 += p*u4.y; c2 += p*u4.z; c3 += p*u4.w; c4 += p*u1;
      }
      float rinv = 1.f / ls;
      s_c[h][i][0]=c0*rinv; s_c[h][i][1]=c1*rinv; s_c[h][i][2]=c2*rinv;
      s_c[h][i][3]=c3*rinv; s_c[h][i][4]=c4*rinv;
    }
    __syncthreads();

    // ---- token pass: sum heads, +res, LN1, FFN(relu), +res, LN2 ----
    if (t < NTOK) {
      int i = t;
      float4 o4 = s_o4[i]; float2 o2 = s_o2[i];
      float o[5] = {o4.x, o4.y, o4.z, o4.w, o2.x};
      float y[5];
      #pragma unroll
      for (int e = 0; e < 5; ++e)
        y[e] = o[e] + s_c[0][i][e] + s_c[1][i][e] + s_c[2][i][e] + s_c[3][i][e];
      float mu = 0.2f*(y[0]+y[1]+y[2]+y[3]+y[4]);
      float var = 0.f;
      #pragma unroll
      for (int e = 0; e < 5; ++e) { float d = y[e]-mu; var += d*d; }
      var *= 0.2f;
      float inv = 1.f / sqrtf(var + 1e-5f);
      float ln1[5];
      #pragma unroll
      for (int e = 0; e < 5; ++e) ln1[e] = (y[e]-mu)*inv*g1[l*5+e] + b1[l*5+e];
      float r2[5];
      #pragma unroll
      for (int e = 0; e < 5; ++e) {
        float acc = bf[l*5+e];
        #pragma unroll
        for (int f = 0; f < 5; ++f) acc += ln1[f]*Wf[(l*5+e)*5+f];
        acc = acc > 0.f ? acc : 0.f;   // relu
        r2[e] = acc + ln1[e];
      }
      float mu2 = 0.2f*(r2[0]+r2[1]+r2[2]+r2[3]+r2[4]);
      float var2 = 0.f;
      #pragma unroll
      for (int e = 0; e < 5; ++e) { float d = r2[e]-mu2; var2 += d*d; }
      var2 *= 0.2f;
      float inv2 = 1.f / sqrtf(var2 + 1e-5f);
      float no[5];
      #pragma unroll
      for (int e = 0; e < 5; ++e) no[e] = (r2[e]-mu2)*inv2*g2[l*5+e] + b2[l*5+e];
      s_o4[i] = make_float4(no[0], no[1], no[2], no[3]);
      s_o2[i] = make_float2(no[4], o2.y);   // keep mask
    }
    __syncthreads();
  }

  // ---- write out [B, N, E] ----
  for (int r = t; r < NTOK*EDIM; r += BLK) {
    int i = r / EDIM;
    int e = r - i*EDIM;
    float v = (e < 4) ? ((const float*)&s_o4[i])[e] : s_o2[i].x;
    out[b*(NTOK*EDIM) + r] = v;
  }
}

extern "C" void kernel_launch(void* const* d_in, const int* in_sizes, int n_in,
                              void* d_out, int out_size, void* d_ws, size_t ws_size,
                              hipStream_t stream) {
  const float* x  = (const float*)d_in[0];
  const float* Wq = (const float*)d_in[1];
  const float* Wk = (const float*)d_in[2];
  const float* Wv = (const float*)d_in[3];
  const float* Wo = (const float*)d_in[4];
  const float* Wf = (const float*)d_in[5];
  const float* bf = (const float*)d_in[6];
  const float* g1 = (const float*)d_in[7];
  const float* b1 = (const float*)d_in[8];
  const float* g2 = (const float*)d_in[9];
  const float* b2 = (const float*)d_in[10];
  float* outp = (float*)d_out;

  encoder_kernel<<<1024, BLK, 0, stream>>>(x, Wq, Wk, Wv, Wo, Wf, bf,
                                           g1, b1, g2, b2, outp);
}

// Round 2
// 121.357 us; speedup vs baseline: 1.6215x; 1.6215x over previous
//
#include <hip/hip_runtime.h>
#include <math.h>

#define NTOK 100
#define EDIM 5
#define NH   4
#define NL   3
#define DD   64
#define BLK  256

// ---------------------------------------------------------------------------
// Kernel 1: fold per-head projections into 5x5 matrices (once per launch).
//   M[l][h] = (1/8) * Wq^T Wk          (dots = o M o^T)
//   P[l][h] = Wv^T Wo_h^T              (attn_out contribution = attn @ (o P))
// Layout in ws: float [2][NL][NH][EDIM][8]  (rows padded to 8 for aligned f4)
// ---------------------------------------------------------------------------
__global__ void precompute_mp(const float* __restrict__ Wq,
                              const float* __restrict__ Wk,
                              const float* __restrict__ Wv,
                              const float* __restrict__ Wo,
                              float* __restrict__ mp) {
  int r = blockIdx.x * blockDim.x + threadIdx.x;
  if (r >= 600) return;
  int which = r / 300;
  int q = r % 300;
  int l = q / 100, rem = q % 100;
  int h = rem / 25, ef = rem % 25;
  int e = ef / 5, f = ef % 5;
  float acc = 0.f;
  if (which == 0) {
    const float* wq = Wq + ((l*NH + h)*DD)*EDIM;
    const float* wk = Wk + ((l*NH + h)*DD)*EDIM;
    #pragma unroll 8
    for (int d = 0; d < DD; ++d) acc += wq[d*EDIM + e] * wk[d*EDIM + f];
    acc *= 0.125f;                       // 1/sqrt(64)
  } else {
    const float* wv = Wv + ((l*NH + h)*DD)*EDIM;
    const float* wo = Wo + (l*EDIM + f)*(NH*DD) + h*DD;
    #pragma unroll 8
    for (int d = 0; d < DD; ++d) acc += wv[d*EDIM + e] * wo[d];
  }
  mp[which*960 + ((l*NH + h)*EDIM + e)*8 + f] = acc;
}

// ---------------------------------------------------------------------------
// Kernel 2: one workgroup per batch element, mask-compacted tokens.
// Unmasked tokens contribute; masked tokens are all identical -> 1 rep token.
// ---------------------------------------------------------------------------
__global__ __launch_bounds__(BLK) void encoder_kernel(
    const float* __restrict__ x,
    const float* __restrict__ mp,
    const float* __restrict__ Wf,
    const float* __restrict__ bfv,
    const float* __restrict__ g1,
    const float* __restrict__ b1,
    const float* __restrict__ g2,
    const float* __restrict__ b2,
    float* __restrict__ out)
{
  const int b = blockIdx.x, t = threadIdx.x;

  __shared__ float4 s_MP4[480];            // 1920 floats: M then P
  __shared__ float4 s_o4[NTOK+2];          // token state [0..3]
  __shared__ float  s_o1[NTOK+2];          // token state [4]
  __shared__ float4 s_u4[NH][NTOK+2];      // u = o @ P_h, [0..3]
  __shared__ float  s_u1[NH][NTOK+2];      // u[4]
  __shared__ float  s_c [NH][NTOK+1][EDIM];// per-head attention output
  __shared__ float  s_cs[NH][EDIM];        // column sums of u over unmasked j
  __shared__ int    s_cidx[NTOK];          // token -> compact index (nm if masked)
  __shared__ unsigned long long s_bal[2];

  const float* mpf = (const float*)s_MP4;

  for (int r = t; r < 480; r += BLK) s_MP4[r] = ((const float4*)mp)[r];

  // ---- setup: mask + ballot-based compaction ----
  float k0=0.f, k1=0.f, k2=0.f, msk=0.f;
  if (t < NTOK) {
    k0 = x[b*300 + 3*t];
    k1 = x[b*300 + 3*t + 1];
    k2 = x[b*300 + 3*t + 2];
    msk = (k2 > 0.f) ? 1.f : 0.f;
  }
  unsigned long long bal = __ballot(t < NTOK && msk != 0.f);
  if (t == 0)  s_bal[0] = bal;
  if (t == 64) s_bal[1] = bal;
  __syncthreads();
  const unsigned long long bw0 = s_bal[0], bw1 = s_bal[1];
  const int nm = __popcll(bw0) + __popcll(bw1);   // # unmasked tokens
  if (t < NTOK) {
    int lane = t & 63;
    unsigned long long lm = (lane == 0) ? 0ull : ((1ull << lane) - 1ull);
    int pre = (t < 64) ? __popcll(bw0 & lm) : (__popcll(bw0) + __popcll(bw1 & lm));
    if (msk != 0.f) {
      s_o4[pre] = make_float4(k0, k1, k2, sinf((float)t));
      s_o1[pre] = cosf((float)t);
      s_cidx[t] = pre;
    } else {
      s_cidx[t] = nm;          // masked tokens map to the rep slot
    }
  }
  if (t == 0) {
    s_o4[nm]   = make_float4(0.f,0.f,0.f,0.f); s_o1[nm]   = 0.f;  // rep token
    s_o4[nm+1] = make_float4(0.f,0.f,0.f,0.f); s_o1[nm+1] = 0.f;  // safety pad
  }
  __syncthreads();

  // ---- static task mapping (same across layers): 2 rows per thread, same h
  const int hp   = (nm + 2) >> 1;        // pairs cover nm+1 tokens (incl. rep)
  const int natt = 4 * hp;               // <= 204
  const bool task = (t < natt);
  int h = 0, i0 = 0, i1 = 0, i1r = 0;
  if (task) {
    h = t / hp; i0 = t - h*hp; i1 = i0 + hp;
    i1r = (i1 <= nm) ? i1 : nm;          // clamped read/store index
  }
  const bool iscs = (!task) && (t - natt < 20);
  int csh = 0, cse = 0;
  if (iscs) { int idx = t - natt; csh = idx / 5; cse = idx - csh*5; }

  for (int l = 0; l < NL; ++l) {
    // ---- phase 1: a (registers), u -> LDS ----
    float a0[5], a1[5];
    if (task) {
      const float* Mh = mpf + ((l*NH + h)*EDIM)*8;
      const float* Ph = Mh + 960;
      float4 oA = s_o4[i0];  float oA4 = s_o1[i0];
      float4 oB = s_o4[i1r]; float oB4 = s_o1[i1r];
      float oa[5] = {oA.x, oA.y, oA.z, oA.w, oA4};
      float ob[5] = {oB.x, oB.y, oB.z, oB.w, oB4};
      float u0[5], u1v[5];
      #pragma unroll
      for (int f = 0; f < 5; ++f) { a0[f]=0.f; a1[f]=0.f; u0[f]=0.f; u1v[f]=0.f; }
      #pragma unroll
      for (int e = 0; e < 5; ++e) {
        float4 mr = *(const float4*)(Mh + e*8); float m4 = Mh[e*8+4];
        float4 pr = *(const float4*)(Ph + e*8); float p4 = Ph[e*8+4];
        float va = oa[e], vb = ob[e];
        a0[0] += va*mr.x; a0[1] += va*mr.y; a0[2] += va*mr.z; a0[3] += va*mr.w; a0[4] += va*m4;
        a1[0] += vb*mr.x; a1[1] += vb*mr.y; a1[2] += vb*mr.z; a1[3] += vb*mr.w; a1[4] += vb*m4;
        u0[0] += va*pr.x; u0[1] += va*pr.y; u0[2] += va*pr.z; u0[3] += va*pr.w; u0[4] += va*p4;
        u1v[0]+= vb*pr.x; u1v[1]+= vb*pr.y; u1v[2]+= vb*pr.z; u1v[3]+= vb*pr.w; u1v[4]+= vb*p4;
      }
      s_u4[h][i0]  = make_float4(u0[0], u0[1], u0[2], u0[3]);  s_u1[h][i0]  = u0[4];
      s_u4[h][i1r] = make_float4(u1v[0],u1v[1],u1v[2],u1v[3]); s_u1[h][i1r] = u1v[4];
    }
    __syncthreads();

    // ---- attention: j-loop over unmasked tokens only ----
    if (task) {
      const float4* __restrict__ pu4 = &s_u4[h][0];
      const float*  __restrict__ pu1 = &s_u1[h][0];
      float ls0 = 0.f, ls1 = 0.f;
      float c00=0.f,c01=0.f,c02=0.f,c03=0.f,c04=0.f;
      float c10=0.f,c11=0.f,c12=0.f,c13=0.f,c14=0.f;
      #pragma unroll 4
      for (int j = 0; j < nm; ++j) {
        float4 oj = s_o4[j]; float oe = s_o1[j];
        float4 uj = pu4[j];  float ue = pu1[j];
        float s0 = a0[0]*oj.x + a0[1]*oj.y + a0[2]*oj.z + a0[3]*oj.w + a0[4]*oe;
        float s1 = a1[0]*oj.x + a1[1]*oj.y + a1[2]*oj.z + a1[3]*oj.w + a1[4]*oe;
        float p0 = __expf(s0), p1 = __expf(s1);
        ls0 += p0; ls1 += p1;
        c00 += p0*uj.x; c01 += p0*uj.y; c02 += p0*uj.z; c03 += p0*uj.w; c04 += p0*ue;
        c10 += p1*uj.x; c11 += p1*uj.y; c12 += p1*uj.z; c13 += p1*uj.w; c14 += p1*ue;
      }
      if (i0 < nm) {
        float r0 = 1.f / ls0;
        s_c[h][i0][0]=c00*r0; s_c[h][i0][1]=c01*r0; s_c[h][i0][2]=c02*r0;
        s_c[h][i0][3]=c03*r0; s_c[h][i0][4]=c04*r0;
      }
      if (i1 < nm) {
        float r1 = 1.f / ls1;
        s_c[h][i1][0]=c10*r1; s_c[h][i1][1]=c11*r1; s_c[h][i1][2]=c12*r1;
        s_c[h][i1][3]=c13*r1; s_c[h][i1][4]=c14*r1;
      }
    } else if (iscs) {
      // column sums of u over unmasked j (for the rep/masked-query tokens)
      float acc = 0.f;
      if (cse < 4) { for (int j = 0; j < nm; ++j) acc += ((const float*)&s_u4[csh][j])[cse]; }
      else         { for (int j = 0; j < nm; ++j) acc += s_u1[csh][j]; }
      s_cs[csh][cse] = acc;
    }
    __syncthreads();

    // ---- token pass: heads-sum, +res, LN1, FFN(relu), +res, LN2 ----
    if (t <= nm) {
      int i = t;
      float4 ov = s_o4[i]; float ov4 = s_o1[i];
      float o[5] = {ov.x, ov.y, ov.z, ov.w, ov4};
      float y[5];
      if (i < nm) {
        #pragma unroll
        for (int e = 0; e < 5; ++e)
          y[e] = o[e] + s_c[0][i][e] + s_c[1][i][e] + s_c[2][i][e] + s_c[3][i][e];
      } else {
        // rep (masked) token: uniform 1/100 attention over ALL original tokens
        float w = (float)(NTOK - nm);
        #pragma unroll
        for (int e = 0; e < 5; ++e) {
          float sum = 0.f;
          #pragma unroll
          for (int hh = 0; hh < NH; ++hh) {
            float ur = (e < 4) ? ((const float*)&s_u4[hh][nm])[e] : s_u1[hh][nm];
            sum += s_cs[hh][e] + w*ur;
          }
          y[e] = o[e] + sum * 0.01f;
        }
      }
      float mu = 0.2f*(y[0]+y[1]+y[2]+y[3]+y[4]);
      float var = 0.f;
      #pragma unroll
      for (int e = 0; e < 5; ++e) { float d = y[e]-mu; var += d*d; }
      var *= 0.2f;
      float inv = 1.f / sqrtf(var + 1e-5f);
      float ln1[5];
      #pragma unroll
      for (int e = 0; e < 5; ++e) ln1[e] = (y[e]-mu)*inv*g1[l*5+e] + b1[l*5+e];
      float r2[5];
      #pragma unroll
      for (int e = 0; e < 5; ++e) {
        float acc = bfv[l*5+e];
        #pragma unroll
        for (int f = 0; f < 5; ++f) acc += ln1[f]*Wf[(l*5+e)*5+f];
        acc = acc > 0.f ? acc : 0.f;
        r2[e] = acc + ln1[e];
      }
      float mu2 = 0.2f*(r2[0]+r2[1]+r2[2]+r2[3]+r2[4]);
      float var2 = 0.f;
      #pragma unroll
      for (int e = 0; e < 5; ++e) { float d = r2[e]-mu2; var2 += d*d; }
      var2 *= 0.2f;
      float inv2 = 1.f / sqrtf(var2 + 1e-5f);
      #pragma unroll
      for (int e = 0; e < 5; ++e) {
        float no = (r2[e]-mu2)*inv2*g2[l*5+e] + b2[l*5+e];
        if (e == 0) { float4 tmp = s_o4[i]; tmp.x = no; s_o4[i] = tmp; }
      }
      // (rewrite cleanly to avoid read-modify-write above)
      float no0 = (r2[0]-mu2)*inv2*g2[l*5+0] + b2[l*5+0];
      float no1 = (r2[1]-mu2)*inv2*g2[l*5+1] + b2[l*5+1];
      float no2 = (r2[2]-mu2)*inv2*g2[l*5+2] + b2[l*5+2];
      float no3 = (r2[3]-mu2)*inv2*g2[l*5+3] + b2[l*5+3];
      float no4 = (r2[4]-mu2)*inv2*g2[l*5+4] + b2[l*5+4];
      s_o4[i] = make_float4(no0, no1, no2, no3);
      s_o1[i] = no4;
    }
    __syncthreads();
  }

  // ---- expand compacted state back to [N, E] ----
  for (int r = t; r < NTOK*EDIM; r += BLK) {
    int i = r / EDIM;
    int e = r - i*EDIM;
    int c = s_cidx[i];
    float v = (e < 4) ? ((const float*)&s_o4[c])[e] : s_o1[c];
    out[b*(NTOK*EDIM) + r] = v;
  }
}

extern "C" void kernel_launch(void* const* d_in, const int* in_sizes, int n_in,
                              void* d_out, int out_size, void* d_ws, size_t ws_size,
                              hipStream_t stream) {
  const float* x  = (const float*)d_in[0];
  const float* Wq = (const float*)d_in[1];
  const float* Wk = (const float*)d_in[2];
  const float* Wv = (const float*)d_in[3];
  const float* Wo = (const float*)d_in[4];
  const float* Wf = (const float*)d_in[5];
  const float* bf = (const float*)d_in[6];
  const float* g1 = (const float*)d_in[7];
  const float* b1 = (const float*)d_in[8];
  const float* g2 = (const float*)d_in[9];
  const float* b2 = (const float*)d_in[10];
  float* outp = (float*)d_out;
  float* mp   = (float*)d_ws;   // 1920 floats

  precompute_mp<<<3, BLK, 0, stream>>>(Wq, Wk, Wv, Wo, mp);
  encoder_kernel<<<1024, BLK, 0, stream>>>(x, mp, Wf, bf, g1, b1, g2, b2, outp);
}

// Round 4
// 119.187 us; speedup vs baseline: 1.6510x; 1.0182x over previous
//
#include <hip/hip_runtime.h>
#include <math.h>

#define NTOK 100
#define EDIM 5
#define NH   4
#define NL   3
#define DD   64
#define BLK  256

// ---------------------------------------------------------------------------
// Kernel 1: fold per-head projections into 5x5 matrices.
//   M[l][h] = (1/8) * Wq^T Wk          (dots = o M o^T)
//   P[l][h] = Wv^T Wo_h^T              (attn contribution c = (sum_j p o_j) P / ls)
// One block per (which,l,h); coalesced LDS staging; 24 blocks x 64 threads.
// ws layout: float [2][NL][NH][EDIM][8]
// ---------------------------------------------------------------------------
__global__ void precompute_mp(const float* __restrict__ Wq,
                              const float* __restrict__ Wk,
                              const float* __restrict__ Wv,
                              const float* __restrict__ Wo,
                              float* __restrict__ mp) {
  const int blk = blockIdx.x;            // 24 = which(2) * l(3) * h(4)
  const int which = blk / 12;
  const int rem = blk % 12;
  const int l = rem / 4, h = rem % 4;
  const int t = threadIdx.x;             // 64 threads

  __shared__ float A[320];               // [d*5+e]
  __shared__ float Bsh[320];             // which0: [d*5+f] ; which1: [f*64+d]

  const float* wa = (which ? Wv : Wq) + (l*NH + h)*DD*EDIM;
  for (int r = t; r < 320; r += 64) A[r] = wa[r];
  if (which == 0) {
    const float* wk = Wk + (l*NH + h)*DD*EDIM;
    for (int r = t; r < 320; r += 64) Bsh[r] = wk[r];
  } else {
    for (int r = t; r < 320; r += 64) {
      int f = r >> 6, d = r & 63;
      Bsh[r] = Wo[(l*EDIM + f)*(NH*DD) + h*DD + d];
    }
  }
  __syncthreads();
  if (t < 25) {
    int e = t / 5, f = t % 5;
    float acc = 0.f;
    if (which == 0) {
      #pragma unroll 8
      for (int d = 0; d < DD; ++d) acc += A[d*5+e] * Bsh[d*5+f];
      acc *= 0.125f;
    } else {
      #pragma unroll 8
      for (int d = 0; d < DD; ++d) acc += A[d*5+e] * Bsh[f*64+d];
    }
    mp[which*960 + ((l*NH + h)*EDIM + e)*8 + f] = acc;
  }
}

// ---------------------------------------------------------------------------
// Kernel 2: one workgroup per batch element, mask-compacted tokens,
// w-accumulation (P applied after softmax), adaptive j-split.
// Masked tokens all share one trajectory -> 1 representative token at slot nm.
// Rep (masked-query) row: uniform 1/100 over ALL 100 original tokens, i.e.
//   w_rep = sum_{unmasked j} o_j + (100-nm)*o_rep   (second term added in
//   the token pass -- THIS was the round-3 bug: o_rep != 0 for layers >= 2).
// ---------------------------------------------------------------------------
__global__ __launch_bounds__(BLK) void encoder_kernel(
    const float* __restrict__ x,
    const float* __restrict__ mp,
    const float* __restrict__ Wf,
    const float* __restrict__ bfv,
    const float* __restrict__ g1,
    const float* __restrict__ b1,
    const float* __restrict__ g2,
    const float* __restrict__ b2,
    float* __restrict__ out)
{
  const int b = blockIdx.x, t = threadIdx.x;

  __shared__ float4 s_MP4[480];             // 1920 floats: M then P
  __shared__ float4 s_o4[NTOK+2];           // token state [0..3]
  __shared__ float  s_o1[NTOK+2];           // token state [4]
  __shared__ float4 s_w4[2][NH][NTOK+2];    // w[0..3] per (jgroup,h,i)
  __shared__ float2 s_w2[2][NH][NTOK+2];    // {w[4], ls}
  __shared__ int    s_cidx[NTOK];
  __shared__ unsigned long long s_bal[2];

  const float* mpf = (const float*)s_MP4;

  for (int r = t; r < 480; r += BLK) s_MP4[r] = ((const float4*)mp)[r];

  // ---- setup: mask + ballot-based compaction ----
  float k0=0.f, k1=0.f, k2=0.f, msk=0.f;
  if (t < NTOK) {
    k0 = x[b*300 + 3*t];
    k1 = x[b*300 + 3*t + 1];
    k2 = x[b*300 + 3*t + 2];
    msk = (k2 > 0.f) ? 1.f : 0.f;
  }
  unsigned long long bal = __ballot(t < NTOK && msk != 0.f);
  if (t == 0)  s_bal[0] = bal;
  if (t == 64) s_bal[1] = bal;
  __syncthreads();
  const unsigned long long bw0 = s_bal[0], bw1 = s_bal[1];
  const int nm = __popcll(bw0) + __popcll(bw1);   // # unmasked tokens
  if (t < NTOK) {
    int lane = t & 63;
    unsigned long long lm = (lane == 0) ? 0ull : ((1ull << lane) - 1ull);
    int pre = (t < 64) ? __popcll(bw0 & lm) : (__popcll(bw0) + __popcll(bw1 & lm));
    if (msk != 0.f) {
      s_o4[pre] = make_float4(k0, k1, k2, sinf((float)t));
      s_o1[pre] = cosf((float)t);
      s_cidx[t] = pre;
    } else {
      s_cidx[t] = nm;
    }
  }
  if (t == 0) {
    s_o4[nm]   = make_float4(0.f,0.f,0.f,0.f); s_o1[nm]   = 0.f;  // rep token
    s_o4[nm+1] = make_float4(0.f,0.f,0.f,0.f); s_o1[nm+1] = 0.f;
  }
  __syncthreads();

  // ---- static task mapping: 2 rows/thread, adaptive j-split ----
  const int hp   = (nm + 2) >> 1;          // pairs cover i in [0, nm]
  const int natt = NH * hp;                // threads per j-group (<=204)
  const int nsplit = (2*natt <= BLK) ? 2 : 1;
  const bool task = (t < natt*nsplit);
  int h = 0, i0 = 0, i1 = 0, i1r = 0, jlo = 0, jhi = 0;
  bool rep0 = false, rep1 = false, w1ok = false;
  if (task) {
    int g  = t / natt;
    int tt = t - g*natt;
    h = tt / hp; i0 = tt - h*hp; i1 = i0 + hp;
    i1r = (i1 <= nm) ? i1 : nm;
    w1ok = (i1 <= nm);
    rep0 = (i0 == nm); rep1 = (i1 == nm);
    int jmid = nm >> 1;
    if (nsplit == 2) { jlo = g ? jmid : 0; jhi = g ? nm : jmid; }
    else             { jlo = 0; jhi = nm; }
  }
  const int wg = task ? (t / natt) : 0;

  for (int l = 0; l < NL; ++l) {
    if (task) {
      // a = o @ M_h for both rows (registers only)
      const float* Mh = mpf + ((l*NH + h)*EDIM)*8;
      float4 oA = s_o4[i0];  float oA4 = s_o1[i0];
      float4 oB = s_o4[i1r]; float oB4 = s_o1[i1r];
      float oa[5] = {oA.x, oA.y, oA.z, oA.w, oA4};
      float ob[5] = {oB.x, oB.y, oB.z, oB.w, oB4};
      float a0[5], a1[5];
      #pragma unroll
      for (int f = 0; f < 5; ++f) { a0[f] = 0.f; a1[f] = 0.f; }
      #pragma unroll
      for (int e = 0; e < 5; ++e) {
        float4 mr = *(const float4*)(Mh + e*8); float m4 = Mh[e*8+4];
        float va = oa[e], vb = ob[e];
        a0[0] += va*mr.x; a0[1] += va*mr.y; a0[2] += va*mr.z; a0[3] += va*mr.w; a0[4] += va*m4;
        a1[0] += vb*mr.x; a1[1] += vb*mr.y; a1[2] += vb*mr.z; a1[3] += vb*mr.w; a1[4] += vb*m4;
      }

      // attention j-loop: accumulate w = sum_j p * o_j  (5 floats) + ls
      float ls0=0.f, ls1=0.f;
      float w00=0.f,w01=0.f,w02=0.f,w03=0.f,w04=0.f;
      float w10=0.f,w11=0.f,w12=0.f,w13=0.f,w14=0.f;
      #pragma unroll 4
      for (int j = jlo; j < jhi; ++j) {
        float4 oj = s_o4[j]; float oe = s_o1[j];
        float s0 = a0[0]*oj.x + a0[1]*oj.y + a0[2]*oj.z + a0[3]*oj.w + a0[4]*oe;
        float s1 = a1[0]*oj.x + a1[1]*oj.y + a1[2]*oj.z + a1[3]*oj.w + a1[4]*oe;
        float p0 = rep0 ? 1.f : __expf(s0);
        float p1 = rep1 ? 1.f : __expf(s1);
        ls0 += p0; ls1 += p1;
        w00 += p0*oj.x; w01 += p0*oj.y; w02 += p0*oj.z; w03 += p0*oj.w; w04 += p0*oe;
        w10 += p1*oj.x; w11 += p1*oj.y; w12 += p1*oj.z; w13 += p1*oj.w; w14 += p1*oe;
      }
      s_w4[wg][h][i0] = make_float4(w00, w01, w02, w03);
      s_w2[wg][h][i0] = make_float2(w04, ls0);
      if (w1ok) {
        s_w4[wg][h][i1] = make_float4(w10, w11, w12, w13);
        s_w2[wg][h][i1] = make_float2(w14, ls1);
      }
    }
    __syncthreads();

    // ---- token pass: apply P per head, +res, LN1, FFN(relu), +res, LN2 ----
    if (t <= nm) {
      int i = t;
      bool rep = (i == nm);
      float4 ov = s_o4[i]; float ov4 = s_o1[i];
      float o[5] = {ov.x, ov.y, ov.z, ov.w, ov4};
      // masked-token correction: uniform row also averages the (100-nm)
      // masked tokens, each carrying the rep state o itself.
      float wext = rep ? (float)(NTOK - nm) : 0.f;
      float c[5] = {0.f, 0.f, 0.f, 0.f, 0.f};
      #pragma unroll
      for (int hh = 0; hh < NH; ++hh) {
        float4 wa = s_w4[0][hh][i]; float2 wb = s_w2[0][hh][i];
        float w[5] = {wa.x, wa.y, wa.z, wa.w, wb.x};
        float ls = wb.y;
        if (nsplit == 2) {
          float4 wa2 = s_w4[1][hh][i]; float2 wb2 = s_w2[1][hh][i];
          w[0] += wa2.x; w[1] += wa2.y; w[2] += wa2.z; w[3] += wa2.w; w[4] += wb2.x;
          ls += wb2.y;
        }
        #pragma unroll
        for (int e = 0; e < 5; ++e) w[e] += wext * o[e];
        float inv = 1.f / (rep ? (float)NTOK : ls);
        const float* Ph = mpf + 960 + ((l*NH + hh)*EDIM)*8;
        #pragma unroll
        for (int e = 0; e < 5; ++e) {
          float4 pr = *(const float4*)(Ph + e*8); float p4 = Ph[e*8+4];
          float we = w[e] * inv;
          c[0] += we*pr.x; c[1] += we*pr.y; c[2] += we*pr.z; c[3] += we*pr.w; c[4] += we*p4;
        }
      }
      float y[5];
      #pragma unroll
      for (int e = 0; e < 5; ++e) y[e] = o[e] + c[e];
      float mu = 0.2f*(y[0]+y[1]+y[2]+y[3]+y[4]);
      float var = 0.f;
      #pragma unroll
      for (int e = 0; e < 5; ++e) { float d = y[e]-mu; var += d*d; }
      var *= 0.2f;
      float inv = 1.f / sqrtf(var + 1e-5f);
      float ln1[5];
      #pragma unroll
      for (int e = 0; e < 5; ++e) ln1[e] = (y[e]-mu)*inv*g1[l*5+e] + b1[l*5+e];
      float r2[5];
      #pragma unroll
      for (int e = 0; e < 5; ++e) {
        float acc = bfv[l*5+e];
        #pragma unroll
        for (int f = 0; f < 5; ++f) acc += ln1[f]*Wf[(l*5+e)*5+f];
        acc = acc > 0.f ? acc : 0.f;
        r2[e] = acc + ln1[e];
      }
      float mu2 = 0.2f*(r2[0]+r2[1]+r2[2]+r2[3]+r2[4]);
      float var2 = 0.f;
      #pragma unroll
      for (int e = 0; e < 5; ++e) { float d = r2[e]-mu2; var2 += d*d; }
      var2 *= 0.2f;
      float inv2 = 1.f / sqrtf(var2 + 1e-5f);
      float no0 = (r2[0]-mu2)*inv2*g2[l*5+0] + b2[l*5+0];
      float no1 = (r2[1]-mu2)*inv2*g2[l*5+1] + b2[l*5+1];
      float no2 = (r2[2]-mu2)*inv2*g2[l*5+2] + b2[l*5+2];
      float no3 = (r2[3]-mu2)*inv2*g2[l*5+3] + b2[l*5+3];
      float no4 = (r2[4]-mu2)*inv2*g2[l*5+4] + b2[l*5+4];
      s_o4[i] = make_float4(no0, no1, no2, no3);
      s_o1[i] = no4;
    }
    __syncthreads();
  }

  // ---- expand compacted state back to [N, E] ----
  for (int r = t; r < NTOK*EDIM; r += BLK) {
    int i = r / EDIM;
    int e = r - i*EDIM;
    int c = s_cidx[i];
    float v = (e < 4) ? ((const float*)&s_o4[c])[e] : s_o1[c];
    out[b*(NTOK*EDIM) + r] = v;
  }
}

extern "C" void kernel_launch(void* const* d_in, const int* in_sizes, int n_in,
                              void* d_out, int out_size, void* d_ws, size_t ws_size,
                              hipStream_t stream) {
  const float* x  = (const float*)d_in[0];
  const float* Wq = (const float*)d_in[1];
  const float* Wk = (const float*)d_in[2];
  const float* Wv = (const float*)d_in[3];
  const float* Wo = (const float*)d_in[4];
  const float* Wf = (const float*)d_in[5];
  const float* bf = (const float*)d_in[6];
  const float* g1 = (const float*)d_in[7];
  const float* b1 = (const float*)d_in[8];
  const float* g2 = (const float*)d_in[9];
  const float* b2 = (const float*)d_in[10];
  float* outp = (float*)d_out;
  float* mp   = (float*)d_ws;   // 1920 floats

  precompute_mp<<<24, 64, 0, stream>>>(Wq, Wk, Wv, Wo, mp);
  encoder_kernel<<<1024, BLK, 0, stream>>>(x, mp, Wf, bf, g1, b1, g2, b2, outp);
}